// Round 2
// baseline (578.601 us; speedup 1.0000x reference)
//
#include <hip/hip_runtime.h>
#include <math.h>

typedef _Float16 f16_t;
typedef _Float16 f16x8 __attribute__((ext_vector_type(8)));
typedef _Float16 f16x4 __attribute__((ext_vector_type(4)));
typedef float    f32x4 __attribute__((ext_vector_type(4)));

#define NHC 128          // NH
#define NBATCH 16
#define JT 64            // output cols per block
#define THREADS 512
#define LDSROWPITCH 272  // 128*2 bytes + 16 pad -> 2-way-max bank aliasing on b128 reads
#define LDSREGION (66*LDSROWPITCH)

__device__ __host__ __forceinline__ int nstep_f(int n){ int m = n - 4; m = m < 0 ? 0 : m; return ((m + 1) >> 1) + 1; }

// ---------------- prep: W[c][i][k] fp32 -> Wt[k][c][i] fp16; depth-channel prefix sums; fp32 bias ----------------
__global__ void prep_kernel(const float* __restrict__ W, const float* __restrict__ bin,
                            f16_t* __restrict__ Wt, float* __restrict__ Pp, float* __restrict__ biasf)
{
    int c = blockIdx.x;      // 0..383
    int i = threadIdx.x;     // 0..127
    #pragma unroll
    for (int k = 0; k < 4; k++)
        Wt[((size_t)k*384 + c)*128 + i] = (f16_t)W[((size_t)c*129 + i)*4 + k];
    if (i == 0) {
        float s = 0.f;
        Pp[c*5 + 0] = 0.f;
        #pragma unroll
        for (int k = 0; k < 4; k++) { s += W[((size_t)c*129 + 128)*4 + k]; Pp[c*5 + k + 1] = s; }
        biasf[c] = bin[c];
    }
}

// ---------------- transpose h (B,NH,L0) fp32 -> X0 (B, pos, 128 ch) fp16, mask p>=N ----------------
__global__ void transpose_kernel(const float* __restrict__ h, const int* __restrict__ N0,
                                 f16_t* __restrict__ X0, int outCols)
{
    __shared__ float tile[32][65];
    const int b = blockIdx.z, c0 = blockIdx.y*32, p0 = blockIdx.x*64;
    const int tid = threadIdx.x;
    const int n0 = N0[b];
    const int L0c = 16384;
    {
        int c = tid >> 3, pc = (tid & 7) * 8;
        const float* src = h + ((size_t)b*NHC + c0 + c)*L0c + p0 + pc;
        float4 v0 = *(const float4*)(src);
        float4 v1 = *(const float4*)(src + 4);
        *(float4*)(&tile[c][pc])     = v0;
        *(float4*)(&tile[c][pc + 4]) = v1;
    }
    __syncthreads();
    {
        int p = tid >> 2, cc = (tid & 3) * 8;
        bool dead = (p0 + p >= n0);
        f16x8 vv;
        #pragma unroll
        for (int e = 0; e < 8; e++) vv[e] = dead ? (f16_t)0.f : (f16_t)tile[cc + e][p];
        *(f16x8*)(X0 + ((size_t)b*outCols + p0 + p)*NHC + c0 + cc) = vv;
    }
}

// ---------------- A-operand fragments held in registers: [tap k][kc chunk][segment l/r/g] ----------------
struct AFrag { f16x8 a[4][4][3]; };   // 48 x f16x8 = 96 VGPRs

__device__ __forceinline__ void load_afrag(AFrag& A, const f16_t* __restrict__ Wt, int arow, int q)
{
    #pragma unroll
    for (int k = 0; k < 4; k++) {
        const f16_t* ab = Wt + ((size_t)k*384 + arow)*128 + q*8;
        #pragma unroll
        for (int kc = 0; kc < 4; kc++) {
            A.a[k][kc][0] = *(const f16x8*)(ab + kc*32);
            A.a[k][kc][1] = *(const f16x8*)(ab + 16384 + kc*32);   // +128 rows
            A.a[k][kc][2] = *(const f16x8*)(ab + 32768 + kc*32);   // +256 rows
        }
    }
}

__device__ __forceinline__ void load_biasp(float (&biasr)[3][4], float (&pfull)[3][4],
                                           const float* __restrict__ biasf,
                                           const float* __restrict__ Pp, int cw)
{
    #pragma unroll
    for (int s = 0; s < 3; s++)
        #pragma unroll
        for (int r = 0; r < 4; r++) {
            int row = s*128 + cw + r;
            biasr[s][r] = biasf[row];
            pfull[s][r] = Pp[row*5 + 4];
        }
}

// ---------------- GEMM inner: pure LDS reads + MFMA, A in registers, CTM live column-tiles ----------------
template<int CTM>
__device__ __forceinline__ void gemm_regA(f32x4 (&acc)[3][4], const AFrag& A,
                                          const char* ldsIn, int n16, int q)
{
    #pragma unroll
    for (int k = 0; k < 4; k++) {
        const char* bb0 = ldsIn + (k&1)*LDSREGION + ((k>>1) + n16)*LDSROWPITCH + q*16;
        #pragma unroll
        for (int kc = 0; kc < 4; kc++) {
            #pragma unroll
            for (int ct = 0; ct < CTM; ct++) {
                f16x8 bb = *(const f16x8*)(bb0 + ct*(16*LDSROWPITCH) + kc*64);
                acc[0][ct] = __builtin_amdgcn_mfma_f32_16x16x32_f16(A.a[k][kc][0], bb, acc[0][ct], 0, 0, 0);
                acc[1][ct] = __builtin_amdgcn_mfma_f32_16x16x32_f16(A.a[k][kc][1], bb, acc[1][ct], 0, 0, 0);
                acc[2][ct] = __builtin_amdgcn_mfma_f32_16x16x32_f16(A.a[k][kc][2], bb, acc[2][ct], 0, 0, 0);
            }
        }
    }
}

// ---------------- gated epilogue; CTE column-tiles (skipped tiles must be all-masked) ----------------
template<int CTE, bool TO_LDS>
__device__ __forceinline__ void epilogue_store(
    const f32x4 (&acc)[3][4], char* ldsOut, f16_t* goutB,
    const float (&biasr)[3][4], const float (&pfull)[3][4],
    const float* __restrict__ Pp, float* __restrict__ outrow,
    int j0, int Nt, int Nt1, float dval, bool record, int n16, int cw)
{
    #pragma unroll
    for (int ct = 0; ct < CTE; ct++) {
        int j = j0 + ct*16 + n16;
        int cnt = Nt - 2*j; cnt = cnt < 0 ? 0 : (cnt > 4 ? 4 : cnt);
        bool zero = (j >= Nt1);
        float hv[4];
        #pragma unroll
        for (int r = 0; r < 4; r++) {
            float d0, d1, d2;
            if (cnt == 4)      { d0 = pfull[0][r]; d1 = pfull[1][r]; d2 = pfull[2][r]; }
            else if (cnt == 0) { d0 = 0.f; d1 = 0.f; d2 = 0.f; }
            else { int rw = cw + r; d0 = Pp[rw*5 + cnt]; d1 = Pp[(128+rw)*5 + cnt]; d2 = Pp[(256+rw)*5 + cnt]; }
            float lv = acc[0][ct][r] + biasr[0][r] + dval*d0;
            float rp = acc[1][ct][r] + biasr[1][r] + dval*d1;
            float gp = acc[2][ct][r] + biasr[2][r] + dval*d2;
            float e2 = __expf(2.f*rp);
            float rv = 1.f - 2.f/(e2 + 1.f);          // tanh
            float gv = 1.f/(1.f + __expf(-gp));       // sigmoid
            float hh = lv*gv + rv*(1.f - gv);
            hv[r] = zero ? 0.f : hh;
        }
        f16x4 hb;
        #pragma unroll
        for (int r = 0; r < 4; r++) hb[r] = (f16_t)hv[r];
        if constexpr (TO_LDS) {
            *(f16x4*)(ldsOut + (j&1)*LDSREGION + (j>>1)*LDSROWPITCH + cw*2) = hb;
        } else {
            *(f16x4*)(goutB + (ct*16 + n16)*NHC + cw) = hb;
        }
        if (record && ct == 0 && n16 == 0) {
            #pragma unroll
            for (int r = 0; r < 4; r++) outrow[cw + r] = hv[r];
        }
    }
}

// ---------------- one conv depth: X_t -> X_{t+1} ----------------
__global__ __launch_bounds__(THREADS) void conv_kernel(
    const f16_t* __restrict__ Xin, f16_t* __restrict__ Xout,
    const f16_t* __restrict__ Wt, const float* __restrict__ Pp,
    const float* __restrict__ biasf, const int* __restrict__ N0,
    float* __restrict__ outbuf,
    int t, int inCols, int outCols, float dval)
{
    __shared__ alignas(16) char ldsX[2*LDSREGION];
    const int b  = blockIdx.y;
    const int j0 = blockIdx.x * JT;
    const int tid = threadIdx.x;
    int Nt = N0[b];
    for (int s = 0; s < t; s++) Nt = nstep_f(Nt);
    const int Nt1 = nstep_f(Nt);

    f16_t* XoutB = Xout + ((size_t)b*outCols + j0)*NHC;
    if (j0 >= Nt1) {                         // fully-masked tile: just zero it
        float4 z = {0.f,0.f,0.f,0.f};
        float4* p = (float4*)XoutB;
        #pragma unroll
        for (int i = 0; i < 2; i++) p[i*THREADS + tid] = z;
        return;
    }

    const int w    = tid >> 6;
    const int lane = tid & 63;
    const int n16  = lane & 15;
    const int q    = lane >> 4;
    const int arow = w*16 + n16;
    const int cw   = w*16 + q*4;

    // issue all A-fragment + epilogue-constant loads now; latency hides under staging + barrier
    AFrag A;
    load_afrag(A, Wt, arow, q);
    float biasr[3][4], pfull[3][4];
    load_biasp(biasr, pfull, biasf, Pp, cw);

    // stage up to 130 input rows (pos-major, 256B each) into parity-split padded LDS
    const char* XinB = (const char*)(Xin + ((size_t)b*inCols + 2*(size_t)j0)*NHC);
    const int maxrow = inCols - 2*j0;        // rows available in this batch's buffer
    for (int it = 0; it < 5; ++it) {
        int idx = it*THREADS + tid;
        if (idx < 130*16) {
            int row = idx >> 4, cb = (idx & 15) * 16;
            float4 v = {0.f,0.f,0.f,0.f};
            if (row < maxrow) v = *(const float4*)(XinB + row*256 + cb);
            *(float4*)(ldsX + (row&1)*LDSREGION + (row>>1)*LDSROWPITCH + cb) = v;
        }
    }
    __syncthreads();

    f32x4 acc[3][4] = {};
    int ctm = (Nt1 - j0 + 15) >> 4; if (ctm > 4) ctm = 4;   // live column-tiles in this block
    switch (ctm) {
    case 1:  gemm_regA<1>(acc, A, ldsX, n16, q); break;
    case 2:  gemm_regA<2>(acc, A, ldsX, n16, q); break;
    case 3:  gemm_regA<3>(acc, A, ldsX, n16, q); break;
    default: gemm_regA<4>(acc, A, ldsX, n16, q); break;
    }
    // tiles ct >= ctm have j >= Nt1 for every lane -> epilogue's zero flag emits zeros (acc unused)

    bool newly = (Nt1 == 1) && (t == 0 || Nt > 1);
    epilogue_store<4, false>(acc, nullptr, XoutB, biasr, pfull, Pp, outbuf + b*NHC,
                             j0, Nt, Nt1, dval, newly && (j0 == 0), n16, cw);
}

// ---------------- tail: one depth iteration, CTM live column-tiles, A already in registers ----------------
// In-place LDS safety: writes cover cols [0, 16*CTM) with zeros past Nt1; next depth reads rows
// only up to 2*nstep(Nt1)+1 <= 16*CTM-1 (verified for all Nt1), so skipped tiles are never read.
template<int CTM>
__device__ __forceinline__ void tail_iter(
    char* ldsX, const AFrag& A,
    const float (&biasr)[3][4], const float (&pfull)[3][4],
    const float* __restrict__ Pp, float* __restrict__ outrow,
    int n16, int q, int cw, int Nt, int Nt1, float dval, bool newly)
{
    f32x4 acc[3][4] = {};
    gemm_regA<CTM>(acc, A, ldsX, n16, q);
    __syncthreads();   // all LDS reads complete before in-place writes
    epilogue_store<CTM, true>(acc, ldsX, nullptr, biasr, pfull, Pp, outrow,
                              0, Nt, Nt1, dval, newly, n16, cw);
}

// ---------------- tail: depths 7..12 entirely in LDS, one block per batch ----------------
__global__ __launch_bounds__(THREADS) void tail_kernel(
    const f16_t* __restrict__ Xin, const f16_t* __restrict__ Wt,
    const float* __restrict__ Pp, const float* __restrict__ biasf,
    const int* __restrict__ N0, float* __restrict__ outbuf, int inCols)
{
    __shared__ alignas(16) char ldsX[2*LDSREGION];
    const int b = blockIdx.x;
    const int tid = threadIdx.x;
    int Nt = N0[b];
    for (int s = 0; s < 7; s++) Nt = nstep_f(Nt);
    if (Nt <= 1) return;                     // finished during conv phase; already recorded

    const int w    = tid >> 6;
    const int lane = tid & 63;
    const int n16  = lane & 15;
    const int q    = lane >> 4;
    const int arow = w*16 + n16;
    const int cw   = w*16 + q*4;
    float* outrow  = outbuf + b*NHC;

    // A-fragments + epilogue constants loaded ONCE for all 6 depths; latency hides under staging
    AFrag A;
    load_afrag(A, Wt, arow, q);
    float biasr[3][4], pfull[3][4];
    load_biasp(biasr, pfull, biasf, Pp, cw);

    const char* XinB = (const char*)(Xin + (size_t)b*inCols*NHC);
    for (int it = 0; it < 5; ++it) {
        int idx = it*THREADS + tid;
        if (idx < 130*16) {
            int row = idx >> 4, cb = (idx & 15) * 16;
            float4 v = {0.f,0.f,0.f,0.f};
            if (row < inCols) v = *(const float4*)(XinB + row*256 + cb);
            *(float4*)(ldsX + (row&1)*LDSREGION + (row>>1)*LDSROWPITCH + cb) = v;
        }
    }
    __syncthreads();

    for (int t = 7; t < 13; ++t) {
        int Nt1 = nstep_f(Nt);
        bool newly = (Nt1 == 1);             // Nt > 1 guaranteed inside the loop
        float dval = log1pf((float)t);
        int ctmax = (Nt1 >> 4) + 1; if (ctmax > 4) ctmax = 4;
        switch (ctmax) {
        case 1:  tail_iter<1>(ldsX, A, biasr, pfull, Pp, outrow, n16, q, cw, Nt, Nt1, dval, newly); break;
        case 2:  tail_iter<2>(ldsX, A, biasr, pfull, Pp, outrow, n16, q, cw, Nt, Nt1, dval, newly); break;
        case 3:  tail_iter<3>(ldsX, A, biasr, pfull, Pp, outrow, n16, q, cw, Nt, Nt1, dval, newly); break;
        default: tail_iter<4>(ldsX, A, biasr, pfull, Pp, outrow, n16, q, cw, Nt, Nt1, dval, newly); break;
        }
        if (newly) return;                   // result recorded; this batch is done
        Nt = Nt1;
        __syncthreads();                     // writes visible before next depth's reads
    }
}

// ---------------- finalize: stable rank by finish depth, emit fp32 ----------------
__global__ void finalize_kernel(const float* __restrict__ outbuf,
                                const int* __restrict__ N0, float* __restrict__ dout)
{
    __shared__ int fin[16];
    __shared__ int rnk[16];
    int tid = threadIdx.x;
    if (tid < 16) {
        int n = N0[tid]; int f = 12;
        for (int t = 0; t < 13; t++) { n = nstep_f(n); if (n == 1) { f = t; break; } }
        fin[tid] = f;
    }
    __syncthreads();
    if (tid < 16) {
        int r = 0;
        for (int b2 = 0; b2 < 16; b2++)
            if (fin[b2] < fin[tid] || (fin[b2] == fin[tid] && b2 < tid)) r++;
        rnk[tid] = r;
    }
    __syncthreads();
    for (int e = tid; e < NBATCH*NHC; e += 256) {
        int b = e >> 7, c = e & 127;
        dout[rnk[b]*NHC + c] = outbuf[e];
    }
}

extern "C" void kernel_launch(void* const* d_in, const int* in_sizes, int n_in,
                              void* d_out, int out_size, void* d_ws, size_t ws_size,
                              hipStream_t stream)
{
    const float* h    = (const float*)d_in[0];
    const int*   N0   = (const int*)d_in[1];
    const float* W    = (const float*)d_in[2];
    const float* bvec = (const float*)d_in[3];
    float* dout = (float*)d_out;

    int Ls[14], Ms[14];
    Ls[0] = 16384;
    for (int t = 0; t < 13; t++) Ls[t+1] = nstep_f(Ls[t]);
    for (int t = 0; t < 14; t++) Ms[t] = ((Ls[t] + 63) / 64) * 64;

    char* ws = (char*)d_ws;
    size_t off = 0;
    auto alloc = [&](size_t bytes){ size_t o = off; off += (bytes + 255) & ~(size_t)255; return o; };
    size_t oXA   = alloc((size_t)NBATCH * Ms[0] * NHC * 2);
    size_t oXB   = alloc((size_t)NBATCH * Ms[1] * NHC * 2);
    size_t oWt   = alloc((size_t)4*384*128*2);
    size_t oPp   = alloc((size_t)384*5*4);
    size_t oBias = alloc((size_t)384*4);
    size_t oOut  = alloc((size_t)NBATCH*NHC*4);
    f16_t* XA    = (f16_t*)(ws + oXA);
    f16_t* XB    = (f16_t*)(ws + oXB);
    f16_t* Wt    = (f16_t*)(ws + oWt);
    float* Pp    = (float*)(ws + oPp);
    float* biasf = (float*)(ws + oBias);
    float* outb  = (float*)(ws + oOut);

    hipLaunchKernelGGL(prep_kernel, dim3(384), dim3(128), 0, stream, W, bvec, Wt, Pp, biasf);
    hipLaunchKernelGGL(transpose_kernel, dim3(Ms[0]/64, 4, NBATCH), dim3(256), 0, stream, h, N0, XA, Ms[0]);

    f16_t* cur = XA; f16_t* nxt = XB;
    for (int t = 0; t < 7; t++) {
        hipLaunchKernelGGL(conv_kernel, dim3(Ms[t+1]/64, NBATCH), dim3(THREADS), 0, stream,
                           cur, nxt, Wt, Pp, biasf, N0, outb, t, Ms[t], Ms[t+1], log1pf((float)t));
        f16_t* tmp = cur; cur = nxt; nxt = tmp;
    }
    // cur == X7
    hipLaunchKernelGGL(tail_kernel, dim3(NBATCH), dim3(THREADS), 0, stream,
                       cur, Wt, Pp, biasf, N0, outb, Ms[7]);
    hipLaunchKernelGGL(finalize_kernel, dim3(1), dim3(256), 0, stream, outb, N0, dout);
}

// Round 3
// 498.647 us; speedup vs baseline: 1.1603x; 1.1603x over previous
//
#include <hip/hip_runtime.h>
#include <math.h>

typedef _Float16 f16_t;
typedef _Float16 f16x8 __attribute__((ext_vector_type(8)));
typedef _Float16 f16x4 __attribute__((ext_vector_type(4)));
typedef float    f32x4 __attribute__((ext_vector_type(4)));

#define NHC 128          // NH
#define NBATCH 16
#define JT 64            // output cols per block
#define THREADS 512
#define LDSROWPITCH 272  // 128*2 bytes + 16 pad -> 2-way-max bank aliasing on b128 reads
#define LDSREGION (66*LDSROWPITCH)

__device__ __host__ __forceinline__ int nstep_f(int n){ int m = n - 4; m = m < 0 ? 0 : m; return ((m + 1) >> 1) + 1; }

// ---------------- prep: W[c][i][k] fp32 -> Wt[k][c][i] fp16; depth-channel prefix sums; fp32 bias ----------------
__global__ void prep_kernel(const float* __restrict__ W, const float* __restrict__ bin,
                            f16_t* __restrict__ Wt, float* __restrict__ Pp, float* __restrict__ biasf)
{
    int c = blockIdx.x;      // 0..383
    int i = threadIdx.x;     // 0..127
    #pragma unroll
    for (int k = 0; k < 4; k++)
        Wt[((size_t)k*384 + c)*128 + i] = (f16_t)W[((size_t)c*129 + i)*4 + k];
    if (i == 0) {
        float s = 0.f;
        Pp[c*5 + 0] = 0.f;
        #pragma unroll
        for (int k = 0; k < 4; k++) { s += W[((size_t)c*129 + 128)*4 + k]; Pp[c*5 + k + 1] = s; }
        biasf[c] = bin[c];
    }
}

// ---------------- transpose h (B,NH,L0) fp32 -> X0 (B, pos, 128 ch) fp16, mask p>=N ----------------
__global__ void transpose_kernel(const float* __restrict__ h, const int* __restrict__ N0,
                                 f16_t* __restrict__ X0, int outCols)
{
    __shared__ float tile[32][65];
    const int b = blockIdx.z, c0 = blockIdx.y*32, p0 = blockIdx.x*64;
    const int tid = threadIdx.x;
    const int n0 = N0[b];
    const int L0c = 16384;
    {
        int c = tid >> 3, pc = (tid & 7) * 8;
        const float* src = h + ((size_t)b*NHC + c0 + c)*L0c + p0 + pc;
        float4 v0 = *(const float4*)(src);
        float4 v1 = *(const float4*)(src + 4);
        *(float4*)(&tile[c][pc])     = v0;
        *(float4*)(&tile[c][pc + 4]) = v1;
    }
    __syncthreads();
    {
        int p = tid >> 2, cc = (tid & 3) * 8;
        bool dead = (p0 + p >= n0);
        f16x8 vv;
        #pragma unroll
        for (int e = 0; e < 8; e++) vv[e] = dead ? (f16_t)0.f : (f16_t)tile[cc + e][p];
        *(f16x8*)(X0 + ((size_t)b*outCols + p0 + p)*NHC + c0 + cc) = vv;
    }
}

// ---------------- GEMM: per-tap batched A loads (12 in flight, 48 VGPR), LDS B, CTM live col-tiles ----------------
// #pragma unroll 1 on k keeps only one tap's A-fragments live -> no spill; one vmcnt wait per tap.
template<int CTM>
__device__ __forceinline__ void gemm_tap(f32x4 (&acc)[3][4], const f16_t* __restrict__ Wt,
                                         const char* ldsIn, int arow, int n16, int q)
{
    #pragma unroll 1
    for (int k = 0; k < 4; k++) {
        const f16_t* ab = Wt + ((size_t)k*384 + arow)*128 + q*8;
        f16x8 a0[4], a1[4], a2[4];
        #pragma unroll
        for (int kc = 0; kc < 4; kc++) {
            a0[kc] = *(const f16x8*)(ab + kc*32);
            a1[kc] = *(const f16x8*)(ab + 16384 + kc*32);   // +128 rows
            a2[kc] = *(const f16x8*)(ab + 32768 + kc*32);   // +256 rows
        }
        const char* bb0 = ldsIn + (k&1)*LDSREGION + ((k>>1) + n16)*LDSROWPITCH + q*16;
        #pragma unroll
        for (int kc = 0; kc < 4; kc++) {
            #pragma unroll
            for (int ct = 0; ct < CTM; ct++) {
                f16x8 bb = *(const f16x8*)(bb0 + ct*(16*LDSROWPITCH) + kc*64);
                acc[0][ct] = __builtin_amdgcn_mfma_f32_16x16x32_f16(a0[kc], bb, acc[0][ct], 0, 0, 0);
                acc[1][ct] = __builtin_amdgcn_mfma_f32_16x16x32_f16(a1[kc], bb, acc[1][ct], 0, 0, 0);
                acc[2][ct] = __builtin_amdgcn_mfma_f32_16x16x32_f16(a2[kc], bb, acc[2][ct], 0, 0, 0);
            }
        }
    }
}

__device__ __forceinline__ void load_biasp(float (&biasr)[3][4], float (&pfull)[3][4],
                                           const float* __restrict__ biasf,
                                           const float* __restrict__ Pp, int cw)
{
    #pragma unroll
    for (int s = 0; s < 3; s++)
        #pragma unroll
        for (int r = 0; r < 4; r++) {
            int row = s*128 + cw + r;
            biasr[s][r] = biasf[row];
            pfull[s][r] = Pp[row*5 + 4];
        }
}

// ---------------- gated epilogue; CTE column-tiles (skipped tiles must be all-masked) ----------------
template<int CTE, bool TO_LDS>
__device__ __forceinline__ void epilogue_store(
    const f32x4 (&acc)[3][4], char* ldsOut, f16_t* goutB,
    const float (&biasr)[3][4], const float (&pfull)[3][4],
    const float* __restrict__ Pp, float* __restrict__ outrow,
    int j0, int Nt, int Nt1, float dval, bool record, int n16, int cw)
{
    #pragma unroll
    for (int ct = 0; ct < CTE; ct++) {
        int j = j0 + ct*16 + n16;
        int cnt = Nt - 2*j; cnt = cnt < 0 ? 0 : (cnt > 4 ? 4 : cnt);
        bool zero = (j >= Nt1);
        float hv[4];
        #pragma unroll
        for (int r = 0; r < 4; r++) {
            float d0, d1, d2;
            if (cnt == 4)      { d0 = pfull[0][r]; d1 = pfull[1][r]; d2 = pfull[2][r]; }
            else if (cnt == 0) { d0 = 0.f; d1 = 0.f; d2 = 0.f; }
            else { int rw = cw + r; d0 = Pp[rw*5 + cnt]; d1 = Pp[(128+rw)*5 + cnt]; d2 = Pp[(256+rw)*5 + cnt]; }
            float lv = acc[0][ct][r] + biasr[0][r] + dval*d0;
            float rp = acc[1][ct][r] + biasr[1][r] + dval*d1;
            float gp = acc[2][ct][r] + biasr[2][r] + dval*d2;
            float e2 = __expf(2.f*rp);
            float rv = 1.f - 2.f/(e2 + 1.f);          // tanh
            float gv = 1.f/(1.f + __expf(-gp));       // sigmoid
            float hh = lv*gv + rv*(1.f - gv);
            hv[r] = zero ? 0.f : hh;
        }
        f16x4 hb;
        #pragma unroll
        for (int r = 0; r < 4; r++) hb[r] = (f16_t)hv[r];
        if constexpr (TO_LDS) {
            *(f16x4*)(ldsOut + (j&1)*LDSREGION + (j>>1)*LDSROWPITCH + cw*2) = hb;
        } else {
            *(f16x4*)(goutB + (ct*16 + n16)*NHC + cw) = hb;
        }
        if (record && ct == 0 && n16 == 0) {
            #pragma unroll
            for (int r = 0; r < 4; r++) outrow[cw + r] = hv[r];
        }
    }
}

// ---------------- one conv depth: X_t -> X_{t+1} ----------------
__global__ __launch_bounds__(THREADS) void conv_kernel(
    const f16_t* __restrict__ Xin, f16_t* __restrict__ Xout,
    const f16_t* __restrict__ Wt, const float* __restrict__ Pp,
    const float* __restrict__ biasf, const int* __restrict__ N0,
    float* __restrict__ outbuf,
    int t, int inCols, int outCols, float dval)
{
    __shared__ alignas(16) char ldsX[2*LDSREGION];
    const int b  = blockIdx.y;
    const int j0 = blockIdx.x * JT;
    const int tid = threadIdx.x;
    int Nt = N0[b];
    for (int s = 0; s < t; s++) Nt = nstep_f(Nt);
    const int Nt1 = nstep_f(Nt);

    f16_t* XoutB = Xout + ((size_t)b*outCols + j0)*NHC;
    if (j0 >= Nt1) {                         // fully-masked tile: just zero it
        float4 z = {0.f,0.f,0.f,0.f};
        float4* p = (float4*)XoutB;
        #pragma unroll
        for (int i = 0; i < 2; i++) p[i*THREADS + tid] = z;
        return;
    }

    const int w    = tid >> 6;
    const int lane = tid & 63;
    const int n16  = lane & 15;
    const int q    = lane >> 4;
    const int arow = w*16 + n16;
    const int cw   = w*16 + q*4;

    // stage up to 130 input rows (pos-major, 256B each) into parity-split padded LDS
    const char* XinB = (const char*)(Xin + ((size_t)b*inCols + 2*(size_t)j0)*NHC);
    const int maxrow = inCols - 2*j0;        // rows available in this batch's buffer
    for (int it = 0; it < 5; ++it) {
        int idx = it*THREADS + tid;
        if (idx < 130*16) {
            int row = idx >> 4, cb = (idx & 15) * 16;
            float4 v = {0.f,0.f,0.f,0.f};
            if (row < maxrow) v = *(const float4*)(XinB + row*256 + cb);
            *(float4*)(ldsX + (row&1)*LDSREGION + (row>>1)*LDSROWPITCH + cb) = v;
        }
    }
    __syncthreads();

    f32x4 acc[3][4] = {};
    int ctm = (Nt1 - j0 + 15) >> 4; if (ctm > 4) ctm = 4;   // live column-tiles in this block
    switch (ctm) {
    case 1:  gemm_tap<1>(acc, Wt, ldsX, arow, n16, q); break;
    case 2:  gemm_tap<2>(acc, Wt, ldsX, arow, n16, q); break;
    case 3:  gemm_tap<3>(acc, Wt, ldsX, arow, n16, q); break;
    default: gemm_tap<4>(acc, Wt, ldsX, arow, n16, q); break;
    }
    // tiles ct >= ctm have j >= Nt1 for every lane -> epilogue's zero flag emits zeros (acc unused)

    // epilogue constants loaded after the GEMM so they don't hold registers during it
    float biasr[3][4], pfull[3][4];
    load_biasp(biasr, pfull, biasf, Pp, cw);

    bool newly = (Nt1 == 1) && (t == 0 || Nt > 1);
    epilogue_store<4, false>(acc, nullptr, XoutB, biasr, pfull, Pp, outbuf + b*NHC,
                             j0, Nt, Nt1, dval, newly && (j0 == 0), n16, cw);
}

// ---------------- tail: one depth iteration, CTM live column-tiles ----------------
// In-place LDS safety: writes cover cols [0, 16*CTM) with zeros past Nt1; next depth reads rows
// only up to 2*nstep(Nt1)+1 <= 16*CTM-1 (verified for all Nt1), so skipped tiles are never read.
template<int CTM>
__device__ __forceinline__ void tail_iter(
    char* ldsX, const f16_t* __restrict__ Wt,
    const float (&biasr)[3][4], const float (&pfull)[3][4],
    const float* __restrict__ Pp, float* __restrict__ outrow,
    int n16, int q, int arow, int cw, int Nt, int Nt1, float dval, bool newly)
{
    f32x4 acc[3][4] = {};
    gemm_tap<CTM>(acc, Wt, ldsX, arow, n16, q);
    __syncthreads();   // all LDS reads complete before in-place writes
    epilogue_store<CTM, true>(acc, ldsX, nullptr, biasr, pfull, Pp, outrow,
                              0, Nt, Nt1, dval, newly, n16, cw);
}

// ---------------- tail: depths 7..12 entirely in LDS, one block per batch ----------------
__global__ __launch_bounds__(THREADS) void tail_kernel(
    const f16_t* __restrict__ Xin, const f16_t* __restrict__ Wt,
    const float* __restrict__ Pp, const float* __restrict__ biasf,
    const int* __restrict__ N0, float* __restrict__ outbuf, int inCols)
{
    __shared__ alignas(16) char ldsX[2*LDSREGION];
    const int b = blockIdx.x;
    const int tid = threadIdx.x;
    int Nt = N0[b];
    for (int s = 0; s < 7; s++) Nt = nstep_f(Nt);
    if (Nt <= 1) return;                     // finished during conv phase; already recorded

    const int w    = tid >> 6;
    const int lane = tid & 63;
    const int n16  = lane & 15;
    const int q    = lane >> 4;
    const int arow = w*16 + n16;
    const int cw   = w*16 + q*4;
    float* outrow  = outbuf + b*NHC;

    const char* XinB = (const char*)(Xin + (size_t)b*inCols*NHC);
    for (int it = 0; it < 5; ++it) {
        int idx = it*THREADS + tid;
        if (idx < 130*16) {
            int row = idx >> 4, cb = (idx & 15) * 16;
            float4 v = {0.f,0.f,0.f,0.f};
            if (row < inCols) v = *(const float4*)(XinB + row*256 + cb);
            *(float4*)(ldsX + (row&1)*LDSREGION + (row>>1)*LDSROWPITCH + cb) = v;
        }
    }

    // depth-invariant epilogue parameters, hoisted out of the depth loop
    float biasr[3][4], pfull[3][4];
    load_biasp(biasr, pfull, biasf, Pp, cw);
    __syncthreads();

    for (int t = 7; t < 13; ++t) {
        int Nt1 = nstep_f(Nt);
        bool newly = (Nt1 == 1);             // Nt > 1 guaranteed inside the loop
        float dval = log1pf((float)t);
        int ctmax = (Nt1 >> 4) + 1; if (ctmax > 4) ctmax = 4;
        switch (ctmax) {
        case 1:  tail_iter<1>(ldsX, Wt, biasr, pfull, Pp, outrow, n16, q, arow, cw, Nt, Nt1, dval, newly); break;
        case 2:  tail_iter<2>(ldsX, Wt, biasr, pfull, Pp, outrow, n16, q, arow, cw, Nt, Nt1, dval, newly); break;
        case 3:  tail_iter<3>(ldsX, Wt, biasr, pfull, Pp, outrow, n16, q, arow, cw, Nt, Nt1, dval, newly); break;
        default: tail_iter<4>(ldsX, Wt, biasr, pfull, Pp, outrow, n16, q, arow, cw, Nt, Nt1, dval, newly); break;
        }
        if (newly) return;                   // result recorded; this batch is done
        Nt = Nt1;
        __syncthreads();                     // writes visible before next depth's reads
    }
}

// ---------------- finalize: stable rank by finish depth, emit fp32 ----------------
__global__ void finalize_kernel(const float* __restrict__ outbuf,
                                const int* __restrict__ N0, float* __restrict__ dout)
{
    __shared__ int fin[16];
    __shared__ int rnk[16];
    int tid = threadIdx.x;
    if (tid < 16) {
        int n = N0[tid]; int f = 12;
        for (int t = 0; t < 13; t++) { n = nstep_f(n); if (n == 1) { f = t; break; } }
        fin[tid] = f;
    }
    __syncthreads();
    if (tid < 16) {
        int r = 0;
        for (int b2 = 0; b2 < 16; b2++)
            if (fin[b2] < fin[tid] || (fin[b2] == fin[tid] && b2 < tid)) r++;
        rnk[tid] = r;
    }
    __syncthreads();
    for (int e = tid; e < NBATCH*NHC; e += 256) {
        int b = e >> 7, c = e & 127;
        dout[rnk[b]*NHC + c] = outbuf[e];
    }
}

extern "C" void kernel_launch(void* const* d_in, const int* in_sizes, int n_in,
                              void* d_out, int out_size, void* d_ws, size_t ws_size,
                              hipStream_t stream)
{
    const float* h    = (const float*)d_in[0];
    const int*   N0   = (const int*)d_in[1];
    const float* W    = (const float*)d_in[2];
    const float* bvec = (const float*)d_in[3];
    float* dout = (float*)d_out;

    int Ls[14], Ms[14];
    Ls[0] = 16384;
    for (int t = 0; t < 13; t++) Ls[t+1] = nstep_f(Ls[t]);
    for (int t = 0; t < 14; t++) Ms[t] = ((Ls[t] + 63) / 64) * 64;

    char* ws = (char*)d_ws;
    size_t off = 0;
    auto alloc = [&](size_t bytes){ size_t o = off; off += (bytes + 255) & ~(size_t)255; return o; };
    size_t oXA   = alloc((size_t)NBATCH * Ms[0] * NHC * 2);
    size_t oXB   = alloc((size_t)NBATCH * Ms[1] * NHC * 2);
    size_t oWt   = alloc((size_t)4*384*128*2);
    size_t oPp   = alloc((size_t)384*5*4);
    size_t oBias = alloc((size_t)384*4);
    size_t oOut  = alloc((size_t)NBATCH*NHC*4);
    f16_t* XA    = (f16_t*)(ws + oXA);
    f16_t* XB    = (f16_t*)(ws + oXB);
    f16_t* Wt    = (f16_t*)(ws + oWt);
    float* Pp    = (float*)(ws + oPp);
    float* biasf = (float*)(ws + oBias);
    float* outb  = (float*)(ws + oOut);

    hipLaunchKernelGGL(prep_kernel, dim3(384), dim3(128), 0, stream, W, bvec, Wt, Pp, biasf);
    hipLaunchKernelGGL(transpose_kernel, dim3(Ms[0]/64, 4, NBATCH), dim3(256), 0, stream, h, N0, XA, Ms[0]);

    f16_t* cur = XA; f16_t* nxt = XB;
    for (int t = 0; t < 7; t++) {
        hipLaunchKernelGGL(conv_kernel, dim3(Ms[t+1]/64, NBATCH), dim3(THREADS), 0, stream,
                           cur, nxt, Wt, Pp, biasf, N0, outb, t, Ms[t], Ms[t+1], log1pf((float)t));
        f16_t* tmp = cur; cur = nxt; nxt = tmp;
    }
    // cur == X7
    hipLaunchKernelGGL(tail_kernel, dim3(NBATCH), dim3(THREADS), 0, stream,
                       cur, Wt, Pp, biasf, N0, outb, Ms[7]);
    hipLaunchKernelGGL(finalize_kernel, dim3(1), dim3(256), 0, stream, outb, N0, dout);
}

// Round 4
// 487.092 us; speedup vs baseline: 1.1879x; 1.0237x over previous
//
#include <hip/hip_runtime.h>
#include <math.h>

typedef _Float16 f16_t;
typedef _Float16 f16x8 __attribute__((ext_vector_type(8)));
typedef _Float16 f16x4 __attribute__((ext_vector_type(4)));
typedef float    f32x4 __attribute__((ext_vector_type(4)));

#define NHC 128          // NH
#define NBATCH 16
#define JT 64            // output cols per block
#define THREADS 512
#define L0LEN 16384
#define LDSROWPITCH 272  // 128*2 bytes + 16 pad -> 2-way-max bank aliasing on b128 reads
#define LDSREGION (66*LDSROWPITCH)   // conv: 130 staged rows (65 per parity region + margin)
#define TREGION (130*LDSROWPITCH)    // tail: 256 staged rows (128 per parity region + margin)

__device__ __host__ __forceinline__ int nstep_f(int n){ int m = n - 4; m = m < 0 ? 0 : m; return ((m + 1) >> 1) + 1; }

// ---------------- prep: W[c][i][k] fp32 -> Wt[k][c][i] fp16; depth-channel prefix sums; fp32 bias ----------------
__global__ void prep_kernel(const float* __restrict__ W, const float* __restrict__ bin,
                            f16_t* __restrict__ Wt, float* __restrict__ Pp, float* __restrict__ biasf)
{
    int c = blockIdx.x;      // 0..383
    int i = threadIdx.x;     // 0..127
    #pragma unroll
    for (int k = 0; k < 4; k++)
        Wt[((size_t)k*384 + c)*128 + i] = (f16_t)W[((size_t)c*129 + i)*4 + k];
    if (i == 0) {
        float s = 0.f;
        Pp[c*5 + 0] = 0.f;
        #pragma unroll
        for (int k = 0; k < 4; k++) { s += W[((size_t)c*129 + 128)*4 + k]; Pp[c*5 + k + 1] = s; }
        biasf[c] = bin[c];
    }
}

// ---------------- GEMM: per-tap batched A loads (12 in flight, 48 VGPR), LDS B, CTM live col-tiles ----------------
// #pragma unroll 1 on k keeps only one tap's A-fragments live -> no spill; one vmcnt wait per tap.
// jt = column-tile base (16-col units) for reading the B operand from LDS.
template<int REG, int CTM>
__device__ __forceinline__ void gemm_tap(f32x4 (&acc)[3][4], const f16_t* __restrict__ Wt,
                                         const char* ldsIn, int arow, int n16, int q, int jt)
{
    #pragma unroll 1
    for (int k = 0; k < 4; k++) {
        const f16_t* ab = Wt + ((size_t)k*384 + arow)*128 + q*8;
        f16x8 a0[4], a1[4], a2[4];
        #pragma unroll
        for (int kc = 0; kc < 4; kc++) {
            a0[kc] = *(const f16x8*)(ab + kc*32);
            a1[kc] = *(const f16x8*)(ab + 16384 + kc*32);   // +128 rows
            a2[kc] = *(const f16x8*)(ab + 32768 + kc*32);   // +256 rows
        }
        const char* bb0 = ldsIn + (k&1)*REG + ((k>>1) + n16 + jt*16)*LDSROWPITCH + q*16;
        #pragma unroll
        for (int kc = 0; kc < 4; kc++) {
            #pragma unroll
            for (int ct = 0; ct < CTM; ct++) {
                f16x8 bb = *(const f16x8*)(bb0 + ct*(16*LDSROWPITCH) + kc*64);
                acc[0][ct] = __builtin_amdgcn_mfma_f32_16x16x32_f16(a0[kc], bb, acc[0][ct], 0, 0, 0);
                acc[1][ct] = __builtin_amdgcn_mfma_f32_16x16x32_f16(a1[kc], bb, acc[1][ct], 0, 0, 0);
                acc[2][ct] = __builtin_amdgcn_mfma_f32_16x16x32_f16(a2[kc], bb, acc[2][ct], 0, 0, 0);
            }
        }
    }
}

__device__ __forceinline__ void load_biasp(float (&biasr)[3][4], float (&pfull)[3][4],
                                           const float* __restrict__ biasf,
                                           const float* __restrict__ Pp, int cw)
{
    #pragma unroll
    for (int s = 0; s < 3; s++)
        #pragma unroll
        for (int r = 0; r < 4; r++) {
            int row = s*128 + cw + r;
            biasr[s][r] = biasf[row];
            pfull[s][r] = Pp[row*5 + 4];
        }
}

// ---------------- gated epilogue; CTE column-tiles (skipped tiles must be all-masked) ----------------
template<int REG, int CTE, bool TO_LDS>
__device__ __forceinline__ void epilogue_store(
    const f32x4 (&acc)[3][4], char* ldsOut, f16_t* goutB,
    const float (&biasr)[3][4], const float (&pfull)[3][4],
    const float* __restrict__ Pp, float* __restrict__ outrow,
    int j0, int Nt, int Nt1, float dval, bool record, int n16, int cw)
{
    #pragma unroll
    for (int ct = 0; ct < CTE; ct++) {
        int j = j0 + ct*16 + n16;
        int cnt = Nt - 2*j; cnt = cnt < 0 ? 0 : (cnt > 4 ? 4 : cnt);
        bool zero = (j >= Nt1);
        float hv[4];
        #pragma unroll
        for (int r = 0; r < 4; r++) {
            float d0, d1, d2;
            if (cnt == 4)      { d0 = pfull[0][r]; d1 = pfull[1][r]; d2 = pfull[2][r]; }
            else if (cnt == 0) { d0 = 0.f; d1 = 0.f; d2 = 0.f; }
            else { int rw = cw + r; d0 = Pp[rw*5 + cnt]; d1 = Pp[(128+rw)*5 + cnt]; d2 = Pp[(256+rw)*5 + cnt]; }
            float lv = acc[0][ct][r] + biasr[0][r] + dval*d0;
            float rp = acc[1][ct][r] + biasr[1][r] + dval*d1;
            float gp = acc[2][ct][r] + biasr[2][r] + dval*d2;
            float e2 = __expf(2.f*rp);
            float rv = 1.f - 2.f/(e2 + 1.f);          // tanh
            float gv = 1.f/(1.f + __expf(-gp));       // sigmoid
            float hh = lv*gv + rv*(1.f - gv);
            hv[r] = zero ? 0.f : hh;
        }
        f16x4 hb;
        #pragma unroll
        for (int r = 0; r < 4; r++) hb[r] = (f16_t)hv[r];
        if constexpr (TO_LDS) {
            *(f16x4*)(ldsOut + (j&1)*REG + (j>>1)*LDSROWPITCH + cw*2) = hb;
        } else {
            *(f16x4*)(goutB + (ct*16 + n16)*NHC + cw) = hb;
        }
        if (record && ct == 0 && n16 == 0) {
            #pragma unroll
            for (int r = 0; r < 4; r++) outrow[cw + r] = hv[r];
        }
    }
}

// ---------------- one conv depth: X_t -> X_{t+1}; t==0 reads h directly (fused transpose) ----------------
__global__ __launch_bounds__(THREADS) void conv_kernel(
    const float* __restrict__ h, const f16_t* __restrict__ Xin, f16_t* __restrict__ Xout,
    const f16_t* __restrict__ Wt, const float* __restrict__ Pp,
    const float* __restrict__ biasf, const int* __restrict__ N0,
    float* __restrict__ outbuf,
    int t, int inCols, int outCols, float dval)
{
    __shared__ alignas(16) char ldsX[2*LDSREGION];
    const int b  = blockIdx.y;
    const int j0 = blockIdx.x * JT;
    const int tid = threadIdx.x;
    int Nt = N0[b];
    for (int s = 0; s < t; s++) Nt = nstep_f(Nt);
    const int Nt1 = nstep_f(Nt);

    f16_t* XoutB = Xout + ((size_t)b*outCols + j0)*NHC;
    if (j0 >= Nt1) {                         // fully-masked tile: just zero it
        float4 z = {0.f,0.f,0.f,0.f};
        float4* p = (float4*)XoutB;
        #pragma unroll
        for (int i = 0; i < 2; i++) p[i*THREADS + tid] = z;
        return;
    }

    if (t == 0) {
        // fused transpose staging: h (b, ch, pos fp32) -> parity-split pos-major f16 LDS, mask p>=N
        const float* hB = h + (size_t)b*NHC*L0LEN;
        const int P0 = 2*j0;
        const int jpr = tid & 63;            // position-pair index (wave-contiguous -> coalesced)
        const int s8  = tid >> 6;            // channel slot
        #pragma unroll
        for (int cg = 0; cg < 16; cg++) {
            int c = cg*8 + s8;
            int p = P0 + jpr*2;
            float2 v = {0.f, 0.f};
            if (p + 1 < Nt)      v = *(const float2*)(hB + (size_t)c*L0LEN + p);
            else if (p < Nt)     v.x = hB[(size_t)c*L0LEN + p];
            char* wb = ldsX + jpr*LDSROWPITCH + c*2;
            *(f16_t*)(wb)             = (f16_t)v.x;   // even row 2*jpr
            *(f16_t*)(wb + LDSREGION) = (f16_t)v.y;   // odd  row 2*jpr+1
        }
        if (tid < 128) {                     // halo rows 128,129
            int c = tid;
            int p = P0 + 128;
            float2 v = {0.f, 0.f};
            if (p + 1 < Nt)      v = *(const float2*)(hB + (size_t)c*L0LEN + p);
            else if (p < Nt)     v.x = hB[(size_t)c*L0LEN + p];
            char* wb = ldsX + 64*LDSROWPITCH + c*2;
            *(f16_t*)(wb)             = (f16_t)v.x;
            *(f16_t*)(wb + LDSREGION) = (f16_t)v.y;
        }
    } else {
        // stage up to 130 input rows (pos-major, 256B each) into parity-split padded LDS
        const char* XinB = (const char*)(Xin + ((size_t)b*inCols + 2*(size_t)j0)*NHC);
        const int maxrow = inCols - 2*j0;    // rows available in this batch's buffer
        for (int it = 0; it < 5; ++it) {
            int idx = it*THREADS + tid;
            if (idx < 130*16) {
                int row = idx >> 4, cb = (idx & 15) * 16;
                float4 v = {0.f,0.f,0.f,0.f};
                if (row < maxrow) v = *(const float4*)(XinB + row*256 + cb);
                *(float4*)(ldsX + (row&1)*LDSREGION + (row>>1)*LDSROWPITCH + cb) = v;
            }
        }
    }
    __syncthreads();

    const int w    = tid >> 6;
    const int lane = tid & 63;
    const int n16  = lane & 15;
    const int q    = lane >> 4;
    const int arow = w*16 + n16;
    const int cw   = w*16 + q*4;

    f32x4 acc[3][4] = {};
    int ctm = (Nt1 - j0 + 15) >> 4; if (ctm > 4) ctm = 4;   // live column-tiles in this block
    switch (ctm) {
    case 1:  gemm_tap<LDSREGION,1>(acc, Wt, ldsX, arow, n16, q, 0); break;
    case 2:  gemm_tap<LDSREGION,2>(acc, Wt, ldsX, arow, n16, q, 0); break;
    case 3:  gemm_tap<LDSREGION,3>(acc, Wt, ldsX, arow, n16, q, 0); break;
    default: gemm_tap<LDSREGION,4>(acc, Wt, ldsX, arow, n16, q, 0); break;
    }
    // tiles ct >= ctm have j >= Nt1 for every lane -> epilogue's zero flag emits zeros (acc unused)

    // epilogue constants loaded after the GEMM so they don't hold registers during it
    float biasr[3][4], pfull[3][4];
    load_biasp(biasr, pfull, biasf, Pp, cw);

    bool newly = (Nt1 == 1) && (t == 0 || Nt > 1);
    epilogue_store<LDSREGION,4,false>(acc, nullptr, XoutB, biasr, pfull, Pp, outbuf + b*NHC,
                                      j0, Nt, Nt1, dval, newly && (j0 == 0), n16, cw);
}

// ---------------- tail: one depth iteration, CTM live column-tiles starting at tile jt ----------------
// In-place LDS safety: output col j overwrites LDS row j; reads for pass (jt,CTM) span rows
// [32*jt, 32*jt+2*(16*CTM-1)+3]; writes span rows [16*jt, 16*jt+16*CTM). Cross-pass overlaps are
// disjoint or barrier-gated (see tail_kernel); stale rows feed only masked output cols.
template<int REG, int CTM>
__device__ __forceinline__ void tail_iter(
    char* ldsX, const f16_t* __restrict__ Wt,
    const float (&biasr)[3][4], const float (&pfull)[3][4],
    const float* __restrict__ Pp, float* __restrict__ outrow,
    int n16, int q, int arow, int cw, int jt, int Nt, int Nt1, float dval, bool newly)
{
    f32x4 acc[3][4] = {};
    gemm_tap<REG,CTM>(acc, Wt, ldsX, arow, n16, q, jt);
    __syncthreads();   // all LDS reads complete before in-place writes
    epilogue_store<REG,CTM,true>(acc, ldsX, nullptr, biasr, pfull, Pp, outrow,
                                 jt*16, Nt, Nt1, dval, newly, n16, cw);
}

// ---------------- tail: depths 6..12 entirely in LDS, one block per batch ----------------
__global__ __launch_bounds__(THREADS) void tail_kernel(
    const f16_t* __restrict__ Xin, const f16_t* __restrict__ Wt,
    const float* __restrict__ Pp, const float* __restrict__ biasf,
    const int* __restrict__ N0, float* __restrict__ outbuf, int inCols)
{
    __shared__ alignas(16) char ldsX[2*TREGION];
    const int b = blockIdx.x;
    const int tid = threadIdx.x;
    int Nt = N0[b];
    for (int s = 0; s < 6; s++) Nt = nstep_f(Nt);
    if (Nt <= 1) return;                     // finished during conv phase; already recorded

    const int w    = tid >> 6;
    const int lane = tid & 63;
    const int n16  = lane & 15;
    const int q    = lane >> 4;
    const int arow = w*16 + n16;
    const int cw   = w*16 + q*4;
    float* outrow  = outbuf + b*NHC;

    // stage up to 256 input rows (X6, pos-major) into parity-split padded LDS
    const char* XinB = (const char*)(Xin + (size_t)b*inCols*NHC);
    for (int it = 0; it < 8; ++it) {
        int idx = it*THREADS + tid;          // 256 rows x 16 chunks = 4096 = 8*512
        int row = idx >> 4, cb = (idx & 15) * 16;
        float4 v = {0.f,0.f,0.f,0.f};
        if (row < inCols) v = *(const float4*)(XinB + row*256 + cb);
        *(float4*)(ldsX + (row&1)*TREGION + (row>>1)*LDSROWPITCH + cb) = v;
    }

    // depth-invariant epilogue parameters, hoisted out of the depth loop
    float biasr[3][4], pfull[3][4];
    load_biasp(biasr, pfull, biasf, Pp, cw);
    __syncthreads();

    for (int t = 6; t < 13; ++t) {
        int Nt1 = nstep_f(Nt);
        bool newly = (Nt1 == 1);             // Nt > 1 guaranteed inside the loop
        float dval = log1pf((float)t);
        int ctmax = (Nt1 >> 4) + 1; if (ctmax > 8) ctmax = 8;
        int cA = ctmax > 4 ? 4 : ctmax;
        switch (cA) {
        case 1:  tail_iter<TREGION,1>(ldsX, Wt, biasr, pfull, Pp, outrow, n16, q, arow, cw, 0, Nt, Nt1, dval, newly); break;
        case 2:  tail_iter<TREGION,2>(ldsX, Wt, biasr, pfull, Pp, outrow, n16, q, arow, cw, 0, Nt, Nt1, dval, newly); break;
        case 3:  tail_iter<TREGION,3>(ldsX, Wt, biasr, pfull, Pp, outrow, n16, q, arow, cw, 0, Nt, Nt1, dval, newly); break;
        default: tail_iter<TREGION,4>(ldsX, Wt, biasr, pfull, Pp, outrow, n16, q, arow, cw, 0, Nt, Nt1, dval, newly); break;
        }
        if (ctmax > 4) {                     // t==6 only (Nt1 up to 127)
            switch (ctmax - 4) {
            case 1:  tail_iter<TREGION,1>(ldsX, Wt, biasr, pfull, Pp, outrow, n16, q, arow, cw, 4, Nt, Nt1, dval, false); break;
            case 2:  tail_iter<TREGION,2>(ldsX, Wt, biasr, pfull, Pp, outrow, n16, q, arow, cw, 4, Nt, Nt1, dval, false); break;
            case 3:  tail_iter<TREGION,3>(ldsX, Wt, biasr, pfull, Pp, outrow, n16, q, arow, cw, 4, Nt, Nt1, dval, false); break;
            default: tail_iter<TREGION,4>(ldsX, Wt, biasr, pfull, Pp, outrow, n16, q, arow, cw, 4, Nt, Nt1, dval, false); break;
            }
        }
        if (newly) return;                   // result recorded; this batch is done
        Nt = Nt1;
        __syncthreads();                     // writes visible before next depth's reads
    }
}

// ---------------- finalize: stable rank by finish depth, emit fp32 ----------------
__global__ void finalize_kernel(const float* __restrict__ outbuf,
                                const int* __restrict__ N0, float* __restrict__ dout)
{
    __shared__ int fin[16];
    __shared__ int rnk[16];
    int tid = threadIdx.x;
    if (tid < 16) {
        int n = N0[tid]; int f = 12;
        for (int t = 0; t < 13; t++) { n = nstep_f(n); if (n == 1) { f = t; break; } }
        fin[tid] = f;
    }
    __syncthreads();
    if (tid < 16) {
        int r = 0;
        for (int b2 = 0; b2 < 16; b2++)
            if (fin[b2] < fin[tid] || (fin[b2] == fin[tid] && b2 < tid)) r++;
        rnk[tid] = r;
    }
    __syncthreads();
    for (int e = tid; e < NBATCH*NHC; e += 256) {
        int b = e >> 7, c = e & 127;
        dout[rnk[b]*NHC + c] = outbuf[e];
    }
}

extern "C" void kernel_launch(void* const* d_in, const int* in_sizes, int n_in,
                              void* d_out, int out_size, void* d_ws, size_t ws_size,
                              hipStream_t stream)
{
    const float* h    = (const float*)d_in[0];
    const int*   N0   = (const int*)d_in[1];
    const float* W    = (const float*)d_in[2];
    const float* bvec = (const float*)d_in[3];
    float* dout = (float*)d_out;

    int Ls[14], Ms[14];
    Ls[0] = L0LEN;
    for (int t = 0; t < 13; t++) Ls[t+1] = nstep_f(Ls[t]);
    for (int t = 0; t < 14; t++) Ms[t] = ((Ls[t] + 63) / 64) * 64;

    char* ws = (char*)d_ws;
    size_t off = 0;
    auto alloc = [&](size_t bytes){ size_t o = off; off += (bytes + 255) & ~(size_t)255; return o; };
    size_t oXA   = alloc((size_t)NBATCH * Ms[1] * NHC * 2);   // X1, X3, X5
    size_t oXB   = alloc((size_t)NBATCH * Ms[2] * NHC * 2);   // X2, X4, X6
    size_t oWt   = alloc((size_t)4*384*128*2);
    size_t oPp   = alloc((size_t)384*5*4);
    size_t oBias = alloc((size_t)384*4);
    size_t oOut  = alloc((size_t)NBATCH*NHC*4);
    f16_t* XA    = (f16_t*)(ws + oXA);
    f16_t* XB    = (f16_t*)(ws + oXB);
    f16_t* Wt    = (f16_t*)(ws + oWt);
    float* Pp    = (float*)(ws + oPp);
    float* biasf = (float*)(ws + oBias);
    float* outb  = (float*)(ws + oOut);

    hipLaunchKernelGGL(prep_kernel, dim3(384), dim3(128), 0, stream, W, bvec, Wt, Pp, biasf);

    // t=0 reads h directly (fused transpose); afterwards ping-pong XA/XB
    f16_t* cur = XA; f16_t* nxt = XB;
    hipLaunchKernelGGL(conv_kernel, dim3(Ms[1]/64, NBATCH), dim3(THREADS), 0, stream,
                       h, (const f16_t*)nullptr, XA, Wt, Pp, biasf, N0, outb,
                       0, Ms[0], Ms[1], log1pf(0.f));
    for (int t = 1; t < 6; t++) {
        hipLaunchKernelGGL(conv_kernel, dim3(Ms[t+1]/64, NBATCH), dim3(THREADS), 0, stream,
                           h, cur, nxt, Wt, Pp, biasf, N0, outb, t, Ms[t], Ms[t+1], log1pf((float)t));
        f16_t* tmp = cur; cur = nxt; nxt = tmp;
    }
    // cur == X6 (t=1,3,5 wrote XB,XA,XB -> cur==XB)
    hipLaunchKernelGGL(tail_kernel, dim3(NBATCH), dim3(THREADS), 0, stream,
                       cur, Wt, Pp, biasf, N0, outb, Ms[6]);
    hipLaunchKernelGGL(finalize_kernel, dim3(1), dim3(256), 0, stream, outb, N0, dout);
}